// Round 1
// baseline (43.664 us; speedup 1.0000x reference)
//
#include <hip/hip_runtime.h>
#include <float.h>
#include <math.h>

#define B_   4
#define S_   2048
#define DIN_ 256
#define DH_  128
#define NB_  50
#define RW   4     // rows per wave
#define WPB  4     // waves per block

// ---------------------------------------------------------------------------
// MLP: per wave, RW rows. lane l computes output cols l and l+64 (DH=128).
// x rows staged in LDS (broadcast reads); W reads are coalesced across lanes.
// ---------------------------------------------------------------------------
__global__ __launch_bounds__(256) void mlp_kernel(
    const float* __restrict__ x,      // [B*S, DIN]
    const float* __restrict__ mask,   // [B*S]
    const float* __restrict__ W1, const float* __restrict__ b1,
    const float* __restrict__ g1, const float* __restrict__ be1,
    const float* __restrict__ W2, const float* __restrict__ b2,
    const float* __restrict__ g2, const float* __restrict__ be2,
    const float* __restrict__ W3, const float* __restrict__ b3,
    const float* __restrict__ temp,
    float* __restrict__ out_logits,   // [B*S, NB]
    float* __restrict__ out_probs)    // [B*S, NB]
{
    const int wave = threadIdx.x >> 6;
    const int lane = threadIdx.x & 63;
    const int row0 = (blockIdx.x * WPB + wave) * RW;

    __shared__ float sx[WPB][RW][DIN_];

    // ---- stage x rows into LDS ----
    for (int r = 0; r < RW; ++r) {
        const float* xr = x + (size_t)(row0 + r) * DIN_;
        for (int k = lane; k < DIN_; k += 64)
            sx[wave][r][k] = xr[k];
    }
    __syncthreads();

    // ---- stage 1: h1 = relu(LN(x @ W1 + b1)) ----
    float a0[RW], a1[RW];
#pragma unroll
    for (int r = 0; r < RW; ++r) { a0[r] = 0.f; a1[r] = 0.f; }
    for (int k = 0; k < DIN_; ++k) {
        const float w0 = W1[k * DH_ + lane];
        const float w1 = W1[k * DH_ + 64 + lane];
#pragma unroll
        for (int r = 0; r < RW; ++r) {
            const float xv = sx[wave][r][k];
            a0[r] = fmaf(xv, w0, a0[r]);
            a1[r] = fmaf(xv, w1, a1[r]);
        }
    }
    {
        const float bb0 = b1[lane],      bb1 = b1[lane + 64];
        const float gg0 = g1[lane],      gg1 = g1[lane + 64];
        const float ee0 = be1[lane],     ee1 = be1[lane + 64];
        __syncthreads();
#pragma unroll
        for (int r = 0; r < RW; ++r) {
            float v0 = a0[r] + bb0, v1 = a1[r] + bb1;
            float sum = v0 + v1;
            for (int off = 32; off; off >>= 1) sum += __shfl_xor(sum, off);
            const float mean = sum * (1.f / DH_);
            const float d0 = v0 - mean, d1 = v1 - mean;
            float vs = d0 * d0 + d1 * d1;
            for (int off = 32; off; off >>= 1) vs += __shfl_xor(vs, off);
            const float inv = rsqrtf(vs * (1.f / DH_) + 1e-5f);
            sx[wave][r][lane]      = fmaxf(fmaf(d0 * inv, gg0, ee0), 0.f);
            sx[wave][r][lane + 64] = fmaxf(fmaf(d1 * inv, gg1, ee1), 0.f);
        }
    }
    __syncthreads();

    // ---- stage 2: h2 = relu(LN(h1 @ W2 + b2)) ----
#pragma unroll
    for (int r = 0; r < RW; ++r) { a0[r] = 0.f; a1[r] = 0.f; }
    for (int k = 0; k < DH_; ++k) {
        const float w0 = W2[k * DH_ + lane];
        const float w1 = W2[k * DH_ + 64 + lane];
#pragma unroll
        for (int r = 0; r < RW; ++r) {
            const float hv = sx[wave][r][k];
            a0[r] = fmaf(hv, w0, a0[r]);
            a1[r] = fmaf(hv, w1, a1[r]);
        }
    }
    {
        const float bb0 = b2[lane],      bb1 = b2[lane + 64];
        const float gg0 = g2[lane],      gg1 = g2[lane + 64];
        const float ee0 = be2[lane],     ee1 = be2[lane + 64];
        __syncthreads();
#pragma unroll
        for (int r = 0; r < RW; ++r) {
            float v0 = a0[r] + bb0, v1 = a1[r] + bb1;
            float sum = v0 + v1;
            for (int off = 32; off; off >>= 1) sum += __shfl_xor(sum, off);
            const float mean = sum * (1.f / DH_);
            const float d0 = v0 - mean, d1 = v1 - mean;
            float vs = d0 * d0 + d1 * d1;
            for (int off = 32; off; off >>= 1) vs += __shfl_xor(vs, off);
            const float inv = rsqrtf(vs * (1.f / DH_) + 1e-5f);
            sx[wave][r][lane]      = fmaxf(fmaf(d0 * inv, gg0, ee0), 0.f);
            sx[wave][r][lane + 64] = fmaxf(fmaf(d1 * inv, gg1, ee1), 0.f);
        }
    }
    __syncthreads();

    // ---- stage 3: logits = (h2 @ W3 + b3) / T ; softmax ; mask ----
    const int l3 = (lane < NB_) ? lane : (NB_ - 1);   // clamp to stay in-bounds
    float lg[RW];
#pragma unroll
    for (int r = 0; r < RW; ++r) lg[r] = 0.f;
    for (int k = 0; k < DH_; ++k) {
        const float w = W3[k * NB_ + l3];
#pragma unroll
        for (int r = 0; r < RW; ++r)
            lg[r] = fmaf(sx[wave][r][k], w, lg[r]);
    }
    {
        const float T   = temp[0];
        const float b3v = b3[l3];
#pragma unroll
        for (int r = 0; r < RW; ++r) {
            const float v  = (lg[r] + b3v) / T;
            float vm = (lane < NB_) ? v : -FLT_MAX;
            for (int off = 32; off; off >>= 1) vm = fmaxf(vm, __shfl_xor(vm, off));
            const float e = (lane < NB_) ? expf(v - vm) : 0.f;
            float sm = e;
            for (int off = 32; off; off >>= 1) sm += __shfl_xor(sm, off);
            const float p  = e / sm;
            const float mk = mask[row0 + r];
            if (lane < NB_) {
                out_logits[(size_t)(row0 + r) * NB_ + lane] = v * mk;
                out_probs [(size_t)(row0 + r) * NB_ + lane] = p * mk;
            }
        }
    }
}

// ---------------------------------------------------------------------------
// pLDDT: one wave per residue i; lanes stride over j. Compare d^2 vs t^2
// (0.25/1/4/16/225 exact in fp32) to avoid sqrt.
// ---------------------------------------------------------------------------
__global__ __launch_bounds__(256) void plddt_kernel(
    const float* __restrict__ coords,  // [B, S, 3]
    const float* __restrict__ mask,    // [B, S]
    float* __restrict__ out)           // [B, S]
{
    const int wave = threadIdx.x >> 6;
    const int lane = threadIdx.x & 63;
    const int row  = blockIdx.x * WPB + wave;   // [0, B*S)
    const int b    = row >> 11;                 // / S_
    const int i    = row & (S_ - 1);

    const float* cb = coords + (size_t)b * S_ * 3;
    const float* mb = mask   + (size_t)b * S_;

    const float xi = cb[i * 3 + 0];
    const float yi = cb[i * 3 + 1];
    const float zi = cb[i * 3 + 2];
    const float mi = mb[i];

    float cnt = 0.f, w0 = 0.f, w1 = 0.f, w2 = 0.f, w3 = 0.f;
    if (mi > 0.f) {
        for (int j = lane; j < S_; j += 64) {
            const float dx = xi - cb[j * 3 + 0];
            const float dy = yi - cb[j * 3 + 1];
            const float dz = zi - cb[j * 3 + 2];
            const float d2 = dx * dx + dy * dy + dz * dz;
            if (mb[j] > 0.f && d2 <= 225.f) {
                cnt += 1.f;
                w0 += (d2 <= 0.25f) ? 1.f : 0.f;
                w1 += (d2 <= 1.f)   ? 1.f : 0.f;
                w2 += (d2 <= 4.f)   ? 1.f : 0.f;
                w3 += (d2 <= 16.f)  ? 1.f : 0.f;
            }
        }
    }
    for (int off = 32; off; off >>= 1) {
        cnt += __shfl_xor(cnt, off);
        w0  += __shfl_xor(w0, off);
        w1  += __shfl_xor(w1, off);
        w2  += __shfl_xor(w2, off);
        w3  += __shfl_xor(w3, off);
    }
    if (lane == 0) {
        const float denom = fmaxf(cnt, 1.f);
        const float fs    = (w0 + w1 + w2 + w3) / denom;
        const float p     = (cnt > 0.f) ? fs * 25.f : 0.f;
        out[row] = p * mi;
    }
}

extern "C" void kernel_launch(void* const* d_in, const int* in_sizes, int n_in,
                              void* d_out, int out_size, void* d_ws, size_t ws_size,
                              hipStream_t stream) {
    const float* x      = (const float*)d_in[0];
    const float* coords = (const float*)d_in[1];
    const float* mask   = (const float*)d_in[2];
    const float* W1  = (const float*)d_in[3];
    const float* b1  = (const float*)d_in[4];
    const float* g1  = (const float*)d_in[5];
    const float* be1 = (const float*)d_in[6];
    const float* W2  = (const float*)d_in[7];
    const float* b2  = (const float*)d_in[8];
    const float* g2  = (const float*)d_in[9];
    const float* be2 = (const float*)d_in[10];
    const float* W3  = (const float*)d_in[11];
    const float* b3  = (const float*)d_in[12];
    const float* temp= (const float*)d_in[13];

    float* out        = (float*)d_out;
    float* out_plddt  = out;                                  // [B*S]
    float* out_logits = out + (size_t)B_ * S_;                // [B*S, NB]
    float* out_probs  = out_logits + (size_t)B_ * S_ * NB_;   // [B*S, NB]

    const int rows = B_ * S_;
    mlp_kernel<<<rows / (WPB * RW), 256, 0, stream>>>(
        x, mask, W1, b1, g1, be1, W2, b2, g2, be2, W3, b3, temp,
        out_logits, out_probs);
    plddt_kernel<<<rows / WPB, 256, 0, stream>>>(coords, mask, out_plddt);
}

// Round 2
// 42.152 us; speedup vs baseline: 1.0359x; 1.0359x over previous
//
#include <hip/hip_runtime.h>
#include <float.h>
#include <math.h>

#define B_   4
#define S_   2048
#define DIN_ 256
#define DH_  128
#define NB_  50
#define NBP_ 64      // padded N for stage 3
#define ROWS (B_ * S_)
#define MB   16      // rows per block (MLP)
#define WPB  4       // waves per block

typedef __attribute__((ext_vector_type(8))) short  short8;
typedef __attribute__((ext_vector_type(4))) float  f32x4;

__device__ __forceinline__ unsigned short bf16_rne(float f) {
    unsigned u = __builtin_bit_cast(unsigned, f);
    u = u + 0x7fffu + ((u >> 16) & 1u);
    return (unsigned short)(u >> 16);
}

// split f32 -> (hi, lo) bf16 pair: x ~= hi + lo, |lo| <= 2^-9 |x|
__device__ __forceinline__ void bf16_split(float f, unsigned short& h, unsigned short& l) {
    h = bf16_rne(f);
    float hf = __builtin_bit_cast(float, (unsigned)h << 16);
    l = bf16_rne(f - hf);
}

// ---------------------------------------------------------------------------
// setup: transpose + hi/lo-split weights into ws (u16 elements)
//   Wt1_hi[128][256] @ 0       Wt1_lo @ 32768
//   Wt2_hi[128][128] @ 65536   Wt2_lo @ 81920
//   Wt3_hi[ 64][128] @ 98304   Wt3_lo @ 106496   (cols >= 50 zero-padded)
// total 114688 u16 = 229376 B
// ---------------------------------------------------------------------------
__global__ __launch_bounds__(256) void setup_w(
    const float* __restrict__ W1, const float* __restrict__ W2,
    const float* __restrict__ W3, unsigned short* __restrict__ wt)
{
    int tid = blockIdx.x * 256 + threadIdx.x;
    float v; int dhi, dlo;
    if (tid < 32768) {
        int n = tid >> 8, k = tid & 255;
        v = W1[k * DH_ + n];
        dhi = n * 256 + k; dlo = dhi + 32768;
    } else if (tid < 49152) {
        int t = tid - 32768; int n = t >> 7, k = t & 127;
        v = W2[k * DH_ + n];
        dhi = 65536 + n * 128 + k; dlo = dhi + 16384;
    } else if (tid < 57344) {
        int t = tid - 49152; int n = t >> 7, k = t & 127;
        v = (n < NB_) ? W3[k * NB_ + n] : 0.f;
        dhi = 98304 + n * 128 + k; dlo = dhi + 8192;
    } else return;
    unsigned short h, l; bf16_split(v, h, l);
    wt[dhi] = h; wt[dlo] = l;
}

// ---------------------------------------------------------------------------
// fused MLP: 16 rows/block, 4 waves n-split (32 cols each), MFMA bf16 x3
// ---------------------------------------------------------------------------
__global__ __launch_bounds__(256) void mlp_mfma(
    const float* __restrict__ x, const float* __restrict__ mask,
    const float* __restrict__ b1, const float* __restrict__ g1, const float* __restrict__ be1,
    const float* __restrict__ b2, const float* __restrict__ g2, const float* __restrict__ be2,
    const float* __restrict__ b3, const float* __restrict__ temp,
    const unsigned short* __restrict__ wt,
    float* __restrict__ out_logits, float* __restrict__ out_probs)
{
    __shared__ unsigned short sA_hi[MB * DIN_];   // stage1: [16][256]; reused [16][128] for h
    __shared__ unsigned short sA_lo[MB * DIN_];
    __shared__ float sStats[MB][8];               // [row][wave*2 + {sum,sumsq}]
    __shared__ float sL[MB * NBP_];               // logits f32

    const int tid  = threadIdx.x;
    const int lane = tid & 63;
    const int w    = tid >> 6;          // wave 0..3
    const int m    = lane & 15;         // MFMA row-lane / col-lane
    const int kg   = lane >> 4;         // k-group 0..3
    const int row0 = blockIdx.x * MB;

    // ---- phase 0: stage x[16][256] as swizzled bf16 hi/lo ----
    {
        const int r  = tid >> 4;
        const int kc = (tid & 15) << 4;
        const float* xp = x + (size_t)(row0 + r) * DIN_ + kc;
#pragma unroll
        for (int q = 0; q < 2; ++q) {
            f32x4 a = *(const f32x4*)(xp + q * 8);
            f32x4 b = *(const f32x4*)(xp + q * 8 + 4);
            union { short8 v; unsigned short u[8]; } H, L;
#pragma unroll
            for (int i = 0; i < 8; ++i) {
                float f = (i < 4) ? a[i] : b[i - 4];
                unsigned short hh, ll; bf16_split(f, hh, ll);
                H.u[i] = hh; L.u[i] = ll;
            }
            const int idx = (r * 256 + kc + q * 8) ^ ((r & 7) << 3);
            *(short8*)&sA_hi[idx] = H.v;
            *(short8*)&sA_lo[idx] = L.v;
        }
    }
    __syncthreads();

    const int cb = w * 32;   // wave's column base (stages 1,2)
    f32x4 acc0 = {0.f, 0.f, 0.f, 0.f};
    f32x4 acc1 = {0.f, 0.f, 0.f, 0.f};

    // ---- stage 1 GEMM: [16x256] @ [256x128] ----
    {
        const unsigned short* w1h = wt;
        const unsigned short* w1l = wt + 32768;
        const int n0 = cb + m;
#pragma unroll
        for (int ks = 0; ks < 8; ++ks) {
            const int k0 = ks * 32 + kg * 8;
            const int ia = (m * 256 + k0) ^ ((m & 7) << 3);
            short8 ah = *(const short8*)&sA_hi[ia];
            short8 al = *(const short8*)&sA_lo[ia];
            short8 b0h = *(const short8*)&w1h[n0 * 256 + k0];
            short8 b0l = *(const short8*)&w1l[n0 * 256 + k0];
            short8 b1h_ = *(const short8*)&w1h[(n0 + 16) * 256 + k0];
            short8 b1l_ = *(const short8*)&w1l[(n0 + 16) * 256 + k0];
            acc0 = __builtin_amdgcn_mfma_f32_16x16x32_bf16(ah, b0h, acc0, 0, 0, 0);
            acc0 = __builtin_amdgcn_mfma_f32_16x16x32_bf16(ah, b0l, acc0, 0, 0, 0);
            acc0 = __builtin_amdgcn_mfma_f32_16x16x32_bf16(al, b0h, acc0, 0, 0, 0);
            acc1 = __builtin_amdgcn_mfma_f32_16x16x32_bf16(ah, b1h_, acc1, 0, 0, 0);
            acc1 = __builtin_amdgcn_mfma_f32_16x16x32_bf16(ah, b1l_, acc1, 0, 0, 0);
            acc1 = __builtin_amdgcn_mfma_f32_16x16x32_bf16(al, b1h_, acc1, 0, 0, 0);
        }
    }

    // ---- LN1 + relu -> h1 (bf16 hi/lo, swizzled [16][128]) ----
    {
        const float bb0 = b1[cb + m],      bb1 = b1[cb + 16 + m];
        const float gg0 = g1[cb + m],      gg1 = g1[cb + 16 + m];
        const float ee0 = be1[cb + m],     ee1 = be1[cb + 16 + m];
        float v0[4], v1[4];
#pragma unroll
        for (int j = 0; j < 4; ++j) { v0[j] = acc0[j] + bb0; v1[j] = acc1[j] + bb1; }
#pragma unroll
        for (int j = 0; j < 4; ++j) {
            float sv = v0[j] + v1[j];
            float qv = v0[j] * v0[j] + v1[j] * v1[j];
            for (int off = 1; off < 16; off <<= 1) { sv += __shfl_xor(sv, off); qv += __shfl_xor(qv, off); }
            if (m == 0) { const int r = kg * 4 + j; sStats[r][w * 2] = sv; sStats[r][w * 2 + 1] = qv; }
        }
        __syncthreads();
#pragma unroll
        for (int j = 0; j < 4; ++j) {
            const int r = kg * 4 + j;
            f32x4 s01 = *(const f32x4*)&sStats[r][0];
            f32x4 s23 = *(const f32x4*)&sStats[r][4];
            const float S = s01[0] + s01[2] + s23[0] + s23[2];
            const float Q = s01[1] + s01[3] + s23[1] + s23[3];
            const float mean = S * (1.f / DH_);
            const float inv  = rsqrtf(Q * (1.f / DH_) - mean * mean + 1e-5f);
            const float h0 = fmaxf(fmaf((v0[j] - mean) * inv, gg0, ee0), 0.f);
            const float h1v = fmaxf(fmaf((v1[j] - mean) * inv, gg1, ee1), 0.f);
            unsigned short hh, ll;
            int idx = (r * 128 + cb + m) ^ ((r & 7) << 3);
            bf16_split(h0, hh, ll); sA_hi[idx] = hh; sA_lo[idx] = ll;
            idx = (r * 128 + cb + 16 + m) ^ ((r & 7) << 3);
            bf16_split(h1v, hh, ll); sA_hi[idx] = hh; sA_lo[idx] = ll;
        }
    }
    __syncthreads();

    // ---- stage 2 GEMM: [16x128] @ [128x128] ----
    acc0 = (f32x4){0.f, 0.f, 0.f, 0.f};
    acc1 = (f32x4){0.f, 0.f, 0.f, 0.f};
    {
        const unsigned short* w2h = wt + 65536;
        const unsigned short* w2l = wt + 81920;
        const int n0 = cb + m;
#pragma unroll
        for (int ks = 0; ks < 4; ++ks) {
            const int k0 = ks * 32 + kg * 8;
            const int ia = (m * 128 + k0) ^ ((m & 7) << 3);
            short8 ah = *(const short8*)&sA_hi[ia];
            short8 al = *(const short8*)&sA_lo[ia];
            short8 b0h = *(const short8*)&w2h[n0 * 128 + k0];
            short8 b0l = *(const short8*)&w2l[n0 * 128 + k0];
            short8 b1h_ = *(const short8*)&w2h[(n0 + 16) * 128 + k0];
            short8 b1l_ = *(const short8*)&w2l[(n0 + 16) * 128 + k0];
            acc0 = __builtin_amdgcn_mfma_f32_16x16x32_bf16(ah, b0h, acc0, 0, 0, 0);
            acc0 = __builtin_amdgcn_mfma_f32_16x16x32_bf16(ah, b0l, acc0, 0, 0, 0);
            acc0 = __builtin_amdgcn_mfma_f32_16x16x32_bf16(al, b0h, acc0, 0, 0, 0);
            acc1 = __builtin_amdgcn_mfma_f32_16x16x32_bf16(ah, b1h_, acc1, 0, 0, 0);
            acc1 = __builtin_amdgcn_mfma_f32_16x16x32_bf16(ah, b1l_, acc1, 0, 0, 0);
            acc1 = __builtin_amdgcn_mfma_f32_16x16x32_bf16(al, b1h_, acc1, 0, 0, 0);
        }
    }

    // ---- LN2 + relu -> h2 ----
    {
        const float bb0 = b2[cb + m],      bb1 = b2[cb + 16 + m];
        const float gg0 = g2[cb + m],      gg1 = g2[cb + 16 + m];
        const float ee0 = be2[cb + m],     ee1 = be2[cb + 16 + m];
        float v0[4], v1[4];
#pragma unroll
        for (int j = 0; j < 4; ++j) { v0[j] = acc0[j] + bb0; v1[j] = acc1[j] + bb1; }
#pragma unroll
        for (int j = 0; j < 4; ++j) {
            float sv = v0[j] + v1[j];
            float qv = v0[j] * v0[j] + v1[j] * v1[j];
            for (int off = 1; off < 16; off <<= 1) { sv += __shfl_xor(sv, off); qv += __shfl_xor(qv, off); }
            if (m == 0) { const int r = kg * 4 + j; sStats[r][w * 2] = sv; sStats[r][w * 2 + 1] = qv; }
        }
        __syncthreads();
#pragma unroll
        for (int j = 0; j < 4; ++j) {
            const int r = kg * 4 + j;
            f32x4 s01 = *(const f32x4*)&sStats[r][0];
            f32x4 s23 = *(const f32x4*)&sStats[r][4];
            const float S = s01[0] + s01[2] + s23[0] + s23[2];
            const float Q = s01[1] + s01[3] + s23[1] + s23[3];
            const float mean = S * (1.f / DH_);
            const float inv  = rsqrtf(Q * (1.f / DH_) - mean * mean + 1e-5f);
            const float h0 = fmaxf(fmaf((v0[j] - mean) * inv, gg0, ee0), 0.f);
            const float h1v = fmaxf(fmaf((v1[j] - mean) * inv, gg1, ee1), 0.f);
            unsigned short hh, ll;
            int idx = (r * 128 + cb + m) ^ ((r & 7) << 3);
            bf16_split(h0, hh, ll); sA_hi[idx] = hh; sA_lo[idx] = ll;
            idx = (r * 128 + cb + 16 + m) ^ ((r & 7) << 3);
            bf16_split(h1v, hh, ll); sA_hi[idx] = hh; sA_lo[idx] = ll;
        }
    }
    __syncthreads();

    // ---- stage 3 GEMM: [16x128] @ [128x64padded] ; wave w -> cols w*16.. ----
    acc0 = (f32x4){0.f, 0.f, 0.f, 0.f};
    {
        const unsigned short* w3h = wt + 98304;
        const unsigned short* w3l = wt + 106496;
        const int n0 = w * 16 + m;
#pragma unroll
        for (int ks = 0; ks < 4; ++ks) {
            const int k0 = ks * 32 + kg * 8;
            const int ia = (m * 128 + k0) ^ ((m & 7) << 3);
            short8 ah = *(const short8*)&sA_hi[ia];
            short8 al = *(const short8*)&sA_lo[ia];
            short8 bh = *(const short8*)&w3h[n0 * 128 + k0];
            short8 bl = *(const short8*)&w3l[n0 * 128 + k0];
            acc0 = __builtin_amdgcn_mfma_f32_16x16x32_bf16(ah, bh, acc0, 0, 0, 0);
            acc0 = __builtin_amdgcn_mfma_f32_16x16x32_bf16(ah, bl, acc0, 0, 0, 0);
            acc0 = __builtin_amdgcn_mfma_f32_16x16x32_bf16(al, bh, acc0, 0, 0, 0);
        }
    }
    {
        const int n = w * 16 + m;
        const float bv = (n < NB_) ? b3[n] : 0.f;
        const float invT = 1.f / temp[0];
#pragma unroll
        for (int j = 0; j < 4; ++j) {
            const int r = kg * 4 + j;
            sL[r * NBP_ + n] = (acc0[j] + bv) * invT;
        }
    }
    __syncthreads();

    // ---- softmax over 50 cols + masked stores ----
    {
        const int r  = tid >> 4;
        const int c0 = (tid & 15) * 4;
        f32x4 lg = *(const f32x4*)&sL[r * NBP_ + c0];
        float mx = -FLT_MAX;
#pragma unroll
        for (int i = 0; i < 4; ++i) if (c0 + i < NB_) mx = fmaxf(mx, lg[i]);
        for (int off = 1; off < 16; off <<= 1) mx = fmaxf(mx, __shfl_xor(mx, off));
        float e[4]; float sm = 0.f;
#pragma unroll
        for (int i = 0; i < 4; ++i) { e[i] = (c0 + i < NB_) ? expf(lg[i] - mx) : 0.f; sm += e[i]; }
        for (int off = 1; off < 16; off <<= 1) sm += __shfl_xor(sm, off);
        const float isum = 1.f / sm;
        const float mk = mask[row0 + r];
        float* ol = out_logits + (size_t)(row0 + r) * NB_;
        float* op = out_probs  + (size_t)(row0 + r) * NB_;
#pragma unroll
        for (int i = 0; i < 4; ++i) {
            const int c = c0 + i;
            if (c < NB_) { ol[c] = lg[i] * mk; op[c] = e[i] * isum * mk; }
        }
    }
}

// ---------------------------------------------------------------------------
// pLDDT: one wave per residue i; lanes stride over j (unchanged, passed R1)
// ---------------------------------------------------------------------------
__global__ __launch_bounds__(256) void plddt_kernel(
    const float* __restrict__ coords, const float* __restrict__ mask,
    float* __restrict__ out)
{
    const int wave = threadIdx.x >> 6;
    const int lane = threadIdx.x & 63;
    const int row  = blockIdx.x * WPB + wave;
    const int b    = row >> 11;
    const int i    = row & (S_ - 1);

    const float* cb = coords + (size_t)b * S_ * 3;
    const float* mb = mask   + (size_t)b * S_;

    const float xi = cb[i * 3 + 0];
    const float yi = cb[i * 3 + 1];
    const float zi = cb[i * 3 + 2];
    const float mi = mb[i];

    float cnt = 0.f, w0 = 0.f, w1 = 0.f, w2 = 0.f, w3 = 0.f;
    if (mi > 0.f) {
        for (int j = lane; j < S_; j += 64) {
            const float dx = xi - cb[j * 3 + 0];
            const float dy = yi - cb[j * 3 + 1];
            const float dz = zi - cb[j * 3 + 2];
            const float d2 = dx * dx + dy * dy + dz * dz;
            if (mb[j] > 0.f && d2 <= 225.f) {
                cnt += 1.f;
                w0 += (d2 <= 0.25f) ? 1.f : 0.f;
                w1 += (d2 <= 1.f)   ? 1.f : 0.f;
                w2 += (d2 <= 4.f)   ? 1.f : 0.f;
                w3 += (d2 <= 16.f)  ? 1.f : 0.f;
            }
        }
    }
    for (int off = 32; off; off >>= 1) {
        cnt += __shfl_xor(cnt, off);
        w0  += __shfl_xor(w0, off);
        w1  += __shfl_xor(w1, off);
        w2  += __shfl_xor(w2, off);
        w3  += __shfl_xor(w3, off);
    }
    if (lane == 0) {
        const float denom = fmaxf(cnt, 1.f);
        const float fs    = (w0 + w1 + w2 + w3) / denom;
        out[row] = ((cnt > 0.f) ? fs * 25.f : 0.f) * mi;
    }
}

extern "C" void kernel_launch(void* const* d_in, const int* in_sizes, int n_in,
                              void* d_out, int out_size, void* d_ws, size_t ws_size,
                              hipStream_t stream) {
    const float* x      = (const float*)d_in[0];
    const float* coords = (const float*)d_in[1];
    const float* mask   = (const float*)d_in[2];
    const float* W1  = (const float*)d_in[3];
    const float* b1  = (const float*)d_in[4];
    const float* g1  = (const float*)d_in[5];
    const float* be1 = (const float*)d_in[6];
    const float* W2  = (const float*)d_in[7];
    const float* b2  = (const float*)d_in[8];
    const float* g2  = (const float*)d_in[9];
    const float* be2 = (const float*)d_in[10];
    const float* W3  = (const float*)d_in[11];
    const float* b3  = (const float*)d_in[12];
    const float* temp= (const float*)d_in[13];

    float* out        = (float*)d_out;
    float* out_plddt  = out;
    float* out_logits = out + (size_t)ROWS;
    float* out_probs  = out_logits + (size_t)ROWS * NB_;

    unsigned short* wt = (unsigned short*)d_ws;

    setup_w<<<224, 256, 0, stream>>>(W1, W2, W3, wt);
    mlp_mfma<<<ROWS / MB, 256, 0, stream>>>(
        x, mask, b1, g1, be1, b2, g2, be2, b3, temp, wt, out_logits, out_probs);
    plddt_kernel<<<ROWS / WPB, 256, 0, stream>>>(coords, mask, out_plddt);
}

// Round 3
// 34.509 us; speedup vs baseline: 1.2653x; 1.2215x over previous
//
#include <hip/hip_runtime.h>
#include <float.h>
#include <math.h>

#define B_   4
#define S_   2048
#define DIN_ 256
#define DH_  128
#define NB_  50
#define NBP_ 64
#define ROWS (B_ * S_)
#define MB   16      // rows per block (MLP)

typedef __attribute__((ext_vector_type(8))) short  short8;
typedef __attribute__((ext_vector_type(4))) float  f32x4;

__device__ __forceinline__ unsigned short bf16_rne(float f) {
    unsigned u = __builtin_bit_cast(unsigned, f);
    u = u + 0x7fffu + ((u >> 16) & 1u);
    return (unsigned short)(u >> 16);
}

__device__ __forceinline__ void bf16_split(float f, unsigned short& h, unsigned short& l) {
    h = bf16_rne(f);
    float hf = __builtin_bit_cast(float, (unsigned)h << 16);
    l = bf16_rne(f - hf);
}

// ---------------------------------------------------------------------------
// setup: weights -> MFMA-fragment-ordered bf16 hi/lo in ws.
// Fragment slot t: chunk c = t>>6, lane l = t&63; m=l&15, kg=l>>4.
// Lane (m,kg) of chunk (nt,ks) holds Wt[nt*16+m][ks*32+kg*8 .. +8).
//   W1: 64 chunks (nt*8+ks)  hi @ 0       lo @ 32768   (u16 idx)
//   W2: 32 chunks (nt*4+ks)  hi @ 65536   lo @ 81920
//   W3: 16 chunks (nt*4+ks)  hi @ 98304   lo @ 106496  (cols >= 50 zero)
// ---------------------------------------------------------------------------
__global__ __launch_bounds__(256) void setup_w(
    const float* __restrict__ W1, const float* __restrict__ W2,
    const float* __restrict__ W3, unsigned short* __restrict__ wt)
{
    const int t = blockIdx.x * 256 + threadIdx.x;   // 7168 slots
    const int l = t & 63, m = l & 15, kg = l >> 4;
    float src[8];
    int dhi, dlo;
    if (t < 4096) {
        const int c = t >> 6, nt = c >> 3, ks = c & 7;
        const int n = nt * 16 + m, k = ks * 32 + kg * 8;
#pragma unroll
        for (int i = 0; i < 8; ++i) src[i] = W1[(k + i) * DH_ + n];
        dhi = t * 8; dlo = dhi + 32768;
    } else if (t < 6144) {
        const int s = t - 4096, c = s >> 6, nt = c >> 2, ks = c & 3;
        const int n = nt * 16 + m, k = ks * 32 + kg * 8;
#pragma unroll
        for (int i = 0; i < 8; ++i) src[i] = W2[(k + i) * DH_ + n];
        dhi = 65536 + s * 8; dlo = dhi + 16384;
    } else {
        const int s = t - 6144, c = s >> 6, nt = c >> 2, ks = c & 3;
        const int n = nt * 16 + m, k = ks * 32 + kg * 8;
#pragma unroll
        for (int i = 0; i < 8; ++i) src[i] = (n < NB_) ? W3[(k + i) * NB_ + n] : 0.f;
        dhi = 98304 + s * 8; dlo = dhi + 8192;
    }
    union { short8 v; unsigned short u[8]; } H, L;
#pragma unroll
    for (int i = 0; i < 8; ++i) {
        unsigned short h, lo_; bf16_split(src[i], h, lo_);
        H.u[i] = h; L.u[i] = lo_;
    }
    *(short8*)&wt[dhi] = H.v;
    *(short8*)&wt[dlo] = L.v;
}

// ---------------------------------------------------------------------------
// fused MLP: 16 rows/block, 8 waves; waves n-split 16 cols (stages 1,2).
// B-frag loads are lane-contiguous 1KB reads from the pre-tiled layout.
// ---------------------------------------------------------------------------
__global__ __launch_bounds__(512) void mlp_mfma(
    const float* __restrict__ x, const float* __restrict__ mask,
    const float* __restrict__ b1, const float* __restrict__ g1, const float* __restrict__ be1,
    const float* __restrict__ b2, const float* __restrict__ g2, const float* __restrict__ be2,
    const float* __restrict__ b3, const float* __restrict__ temp,
    const unsigned short* __restrict__ wt,
    float* __restrict__ out_logits, float* __restrict__ out_probs)
{
    __shared__ unsigned short sA_hi[MB * DIN_];
    __shared__ unsigned short sA_lo[MB * DIN_];
    __shared__ float sStats[MB][16];
    __shared__ float sL[MB * NBP_];

    const int tid  = threadIdx.x;
    const int lane = tid & 63;
    const int w    = tid >> 6;          // wave 0..7
    const int m    = lane & 15;
    const int kg   = lane >> 4;
    const int row0 = blockIdx.x * MB;

    // ---- stage x[16][256] as swizzled bf16 hi/lo ----
    {
        const int r  = tid >> 5;            // 16 rows, 32 thr/row
        const int kc = (tid & 31) << 3;     // 8 floats each
        const float* xp = x + (size_t)(row0 + r) * DIN_ + kc;
        f32x4 a = *(const f32x4*)xp;
        f32x4 b = *(const f32x4*)(xp + 4);
        union { short8 v; unsigned short u[8]; } H, L;
#pragma unroll
        for (int i = 0; i < 8; ++i) {
            float f = (i < 4) ? a[i] : b[i - 4];
            unsigned short hh, ll; bf16_split(f, hh, ll);
            H.u[i] = hh; L.u[i] = ll;
        }
        const int idx = (r * 256 + kc) ^ ((r & 7) << 3);
        *(short8*)&sA_hi[idx] = H.v;
        *(short8*)&sA_lo[idx] = L.v;
    }
    __syncthreads();

    const int n12 = w * 16 + m;   // this lane's output col, stages 1,2

    // ---- stage 1 GEMM: [16x256] @ [256x128], wave w -> cols [16w,16w+16) ----
    f32x4 aA = {0.f,0.f,0.f,0.f}, aB = {0.f,0.f,0.f,0.f};
    {
        const unsigned short* bh_p = wt + (w * 8) * 512;
        const unsigned short* bl_p = wt + 32768 + (w * 8) * 512;
#pragma unroll
        for (int ks = 0; ks < 8; ++ks) {
            const int ia = (m * 256 + ks * 32 + kg * 8) ^ ((m & 7) << 3);
            short8 ah = *(const short8*)&sA_hi[ia];
            short8 al = *(const short8*)&sA_lo[ia];
            short8 bh = *(const short8*)&bh_p[ks * 512 + lane * 8];
            short8 bl = *(const short8*)&bl_p[ks * 512 + lane * 8];
            f32x4& ac = (ks & 1) ? aB : aA;
            ac = __builtin_amdgcn_mfma_f32_16x16x32_bf16(ah, bh, ac, 0, 0, 0);
            ac = __builtin_amdgcn_mfma_f32_16x16x32_bf16(ah, bl, ac, 0, 0, 0);
            ac = __builtin_amdgcn_mfma_f32_16x16x32_bf16(al, bh, ac, 0, 0, 0);
        }
    }

    // ---- LN1 + relu -> h1 (bf16 hi/lo, swizzled [16][128]) ----
    {
        const float bb = b1[n12], gg = g1[n12], ee = be1[n12];
        float v[4];
#pragma unroll
        for (int j = 0; j < 4; ++j) v[j] = aA[j] + aB[j] + bb;
#pragma unroll
        for (int j = 0; j < 4; ++j) {
            float sv = v[j], qv = v[j] * v[j];
            for (int off = 1; off < 16; off <<= 1) { sv += __shfl_xor(sv, off); qv += __shfl_xor(qv, off); }
            if (m == 0) { sStats[kg * 4 + j][w * 2] = sv; sStats[kg * 4 + j][w * 2 + 1] = qv; }
        }
        __syncthreads();
#pragma unroll
        for (int j = 0; j < 4; ++j) {
            const int r = kg * 4 + j;
            f32x4 s0 = *(const f32x4*)&sStats[r][0];
            f32x4 s1 = *(const f32x4*)&sStats[r][4];
            f32x4 s2 = *(const f32x4*)&sStats[r][8];
            f32x4 s3 = *(const f32x4*)&sStats[r][12];
            const float S = s0[0]+s0[2]+s1[0]+s1[2]+s2[0]+s2[2]+s3[0]+s3[2];
            const float Q = s0[1]+s0[3]+s1[1]+s1[3]+s2[1]+s2[3]+s3[1]+s3[3];
            const float mean = S * (1.f / DH_);
            const float inv  = rsqrtf(Q * (1.f / DH_) - mean * mean + 1e-5f);
            const float h = fmaxf(fmaf((v[j] - mean) * inv, gg, ee), 0.f);
            unsigned short hh, ll; bf16_split(h, hh, ll);
            const int idx = (r * 128 + n12) ^ ((r & 7) << 3);
            sA_hi[idx] = hh; sA_lo[idx] = ll;
        }
    }
    __syncthreads();

    // ---- stage 2 GEMM: [16x128] @ [128x128] ----
    aA = (f32x4){0.f,0.f,0.f,0.f}; aB = (f32x4){0.f,0.f,0.f,0.f};
    {
        const unsigned short* bh_p = wt + 65536 + (w * 4) * 512;
        const unsigned short* bl_p = wt + 81920 + (w * 4) * 512;
#pragma unroll
        for (int ks = 0; ks < 4; ++ks) {
            const int ia = (m * 128 + ks * 32 + kg * 8) ^ ((m & 7) << 3);
            short8 ah = *(const short8*)&sA_hi[ia];
            short8 al = *(const short8*)&sA_lo[ia];
            short8 bh = *(const short8*)&bh_p[ks * 512 + lane * 8];
            short8 bl = *(const short8*)&bl_p[ks * 512 + lane * 8];
            f32x4& ac = (ks & 1) ? aB : aA;
            ac = __builtin_amdgcn_mfma_f32_16x16x32_bf16(ah, bh, ac, 0, 0, 0);
            ac = __builtin_amdgcn_mfma_f32_16x16x32_bf16(ah, bl, ac, 0, 0, 0);
            ac = __builtin_amdgcn_mfma_f32_16x16x32_bf16(al, bh, ac, 0, 0, 0);
        }
    }

    // ---- LN2 + relu -> h2 ----
    {
        const float bb = b2[n12], gg = g2[n12], ee = be2[n12];
        float v[4];
#pragma unroll
        for (int j = 0; j < 4; ++j) v[j] = aA[j] + aB[j] + bb;
#pragma unroll
        for (int j = 0; j < 4; ++j) {
            float sv = v[j], qv = v[j] * v[j];
            for (int off = 1; off < 16; off <<= 1) { sv += __shfl_xor(sv, off); qv += __shfl_xor(qv, off); }
            if (m == 0) { sStats[kg * 4 + j][w * 2] = sv; sStats[kg * 4 + j][w * 2 + 1] = qv; }
        }
        __syncthreads();
#pragma unroll
        for (int j = 0; j < 4; ++j) {
            const int r = kg * 4 + j;
            f32x4 s0 = *(const f32x4*)&sStats[r][0];
            f32x4 s1 = *(const f32x4*)&sStats[r][4];
            f32x4 s2 = *(const f32x4*)&sStats[r][8];
            f32x4 s3 = *(const f32x4*)&sStats[r][12];
            const float S = s0[0]+s0[2]+s1[0]+s1[2]+s2[0]+s2[2]+s3[0]+s3[2];
            const float Q = s0[1]+s0[3]+s1[1]+s1[3]+s2[1]+s2[3]+s3[1]+s3[3];
            const float mean = S * (1.f / DH_);
            const float inv  = rsqrtf(Q * (1.f / DH_) - mean * mean + 1e-5f);
            const float h = fmaxf(fmaf((v[j] - mean) * inv, gg, ee), 0.f);
            unsigned short hh, ll; bf16_split(h, hh, ll);
            const int idx = (r * 128 + n12) ^ ((r & 7) << 3);
            sA_hi[idx] = hh; sA_lo[idx] = ll;
        }
    }
    __syncthreads();

    // ---- stage 3 GEMM: [16x128] @ [128x64pad], waves 0..3 only ----
    if (w < 4) {
        f32x4 cA = {0.f,0.f,0.f,0.f}, cB = {0.f,0.f,0.f,0.f};
        const unsigned short* bh_p = wt + 98304  + (w * 4) * 512;
        const unsigned short* bl_p = wt + 106496 + (w * 4) * 512;
#pragma unroll
        for (int ks = 0; ks < 4; ++ks) {
            const int ia = (m * 128 + ks * 32 + kg * 8) ^ ((m & 7) << 3);
            short8 ah = *(const short8*)&sA_hi[ia];
            short8 al = *(const short8*)&sA_lo[ia];
            short8 bh = *(const short8*)&bh_p[ks * 512 + lane * 8];
            short8 bl = *(const short8*)&bl_p[ks * 512 + lane * 8];
            f32x4& ac = (ks & 1) ? cB : cA;
            ac = __builtin_amdgcn_mfma_f32_16x16x32_bf16(ah, bh, ac, 0, 0, 0);
            ac = __builtin_amdgcn_mfma_f32_16x16x32_bf16(ah, bl, ac, 0, 0, 0);
            ac = __builtin_amdgcn_mfma_f32_16x16x32_bf16(al, bh, ac, 0, 0, 0);
        }
        const int n = w * 16 + m;
        const float bv = (n < NB_) ? b3[n] : 0.f;
        const float invT = 1.f / temp[0];
#pragma unroll
        for (int j = 0; j < 4; ++j)
            sL[(kg * 4 + j) * NBP_ + n] = (cA[j] + cB[j] + bv) * invT;
    }
    __syncthreads();

    // ---- softmax over 50 cols + masked stores (first 4 waves) ----
    if (tid < 256) {
        const int r  = tid >> 4;
        const int c0 = (tid & 15) * 4;
        f32x4 lg = *(const f32x4*)&sL[r * NBP_ + c0];
        float mx = -FLT_MAX;
#pragma unroll
        for (int i = 0; i < 4; ++i) if (c0 + i < NB_) mx = fmaxf(mx, lg[i]);
        for (int off = 1; off < 16; off <<= 1) mx = fmaxf(mx, __shfl_xor(mx, off));
        float e[4]; float sm = 0.f;
#pragma unroll
        for (int i = 0; i < 4; ++i) { e[i] = (c0 + i < NB_) ? expf(lg[i] - mx) : 0.f; sm += e[i]; }
        for (int off = 1; off < 16; off <<= 1) sm += __shfl_xor(sm, off);
        const float isum = 1.f / sm;
        const float mk = mask[row0 + r];
        float* ol = out_logits + (size_t)(row0 + r) * NB_;
        float* op = out_probs  + (size_t)(row0 + r) * NB_;
#pragma unroll
        for (int i = 0; i < 4; ++i) {
            const int c = c0 + i;
            if (c < NB_) { ol[c] = lg[i] * mk; op[c] = e[i] * isum * mk; }
        }
    }
}

// ---------------------------------------------------------------------------
// pLDDT: LDS-staged float4 (x,y,z,m); 16 rows/block, 4 i's per wave.
// ---------------------------------------------------------------------------
__global__ __launch_bounds__(256) void plddt_kernel(
    const float* __restrict__ coords, const float* __restrict__ mask,
    float* __restrict__ out)
{
    __shared__ f32x4 sP[S_];
    const int tid  = threadIdx.x;
    const int lane = tid & 63;
    const int wave = tid >> 6;
    const int row0 = blockIdx.x * 16;
    const int b    = row0 >> 11;
    const int ib0  = row0 & (S_ - 1);

    const float* cb = coords + (size_t)b * S_ * 3;
    const float* mb = mask   + (size_t)b * S_;

    {   // stage all 2048 points: 8 per thread, vectorized reads
        union { f32x4 v[6]; float f[24]; } C;
        const float* cp = cb + tid * 24;
#pragma unroll
        for (int q = 0; q < 6; ++q) C.v[q] = *(const f32x4*)(cp + q * 4);
        union { f32x4 v[2]; float f[8]; } M;
        M.v[0] = *(const f32x4*)(mb + tid * 8);
        M.v[1] = *(const f32x4*)(mb + tid * 8 + 4);
#pragma unroll
        for (int q = 0; q < 8; ++q)
            sP[tid * 8 + q] = (f32x4){C.f[q*3], C.f[q*3+1], C.f[q*3+2], M.f[q]};
    }
    __syncthreads();

    f32x4 PI[4];
#pragma unroll
    for (int ii = 0; ii < 4; ++ii) PI[ii] = sP[ib0 + wave * 4 + ii];

    int cnt[4] = {0,0,0,0}, ws[4] = {0,0,0,0};
    for (int j = lane; j < S_; j += 64) {
        const f32x4 p = sP[j];
        const float gd = (p[3] > 0.f) ? 0.f : 1e30f;
#pragma unroll
        for (int ii = 0; ii < 4; ++ii) {
            const float dx = PI[ii][0] - p[0];
            const float dy = PI[ii][1] - p[1];
            const float dz = PI[ii][2] - p[2];
            const float d2 = fmaf(dx, dx, fmaf(dy, dy, dz * dz)) + gd;
            cnt[ii] += (d2 <= 225.f);
            ws[ii]  += (d2 <= 16.f);
            ws[ii]  += (d2 <= 4.f);
            ws[ii]  += (d2 <= 1.f);
            ws[ii]  += (d2 <= 0.25f);
        }
    }
#pragma unroll
    for (int ii = 0; ii < 4; ++ii)
        for (int off = 32; off; off >>= 1) {
            cnt[ii] += __shfl_xor(cnt[ii], off);
            ws[ii]  += __shfl_xor(ws[ii], off);
        }
    if (lane == 0) {
#pragma unroll
        for (int ii = 0; ii < 4; ++ii) {
            const float fc = (float)cnt[ii];
            const float r  = (cnt[ii] > 0) ? (ws[ii] * 25.f / fc) : 0.f;
            out[row0 + wave * 4 + ii] = r * PI[ii][3];
        }
    }
}

extern "C" void kernel_launch(void* const* d_in, const int* in_sizes, int n_in,
                              void* d_out, int out_size, void* d_ws, size_t ws_size,
                              hipStream_t stream) {
    const float* x      = (const float*)d_in[0];
    const float* coords = (const float*)d_in[1];
    const float* mask   = (const float*)d_in[2];
    const float* W1  = (const float*)d_in[3];
    const float* b1  = (const float*)d_in[4];
    const float* g1  = (const float*)d_in[5];
    const float* be1 = (const float*)d_in[6];
    const float* W2  = (const float*)d_in[7];
    const float* b2  = (const float*)d_in[8];
    const float* g2  = (const float*)d_in[9];
    const float* be2 = (const float*)d_in[10];
    const float* W3  = (const float*)d_in[11];
    const float* b3  = (const float*)d_in[12];
    const float* temp= (const float*)d_in[13];

    float* out        = (float*)d_out;
    float* out_plddt  = out;
    float* out_logits = out + (size_t)ROWS;
    float* out_probs  = out_logits + (size_t)ROWS * NB_;

    unsigned short* wt = (unsigned short*)d_ws;

    setup_w<<<28, 256, 0, stream>>>(W1, W2, W3, wt);
    mlp_mfma<<<ROWS / MB, 512, 0, stream>>>(
        x, mask, b1, g1, be1, b2, g2, be2, b3, temp, wt, out_logits, out_probs);
    plddt_kernel<<<ROWS / 16, 256, 0, stream>>>(coords, mask, out_plddt);
}